// Round 2
// baseline (208.661 us; speedup 1.0000x reference)
//
#include <hip/hip_runtime.h>
#include <math.h>

// Problem constants: B=16, C_in=256, H=W=32 -> N=1024, qkv_out=1536,
// HEAD=8, dh=dv=64, V_DIM=512, OUT_CH=256.
static constexpr int Bsz = 16;
static constexpr int Np  = 1024;
static constexpr int Cin = 256;

typedef __attribute__((ext_vector_type(8))) short short8;  // 8 bf16 = 4 VGPR
typedef __attribute__((ext_vector_type(4))) float f4;      // mfma acc

// v_exp_f32 computes 2^x natively; use it without the log2e multiply.
#if defined(__has_builtin)
#if __has_builtin(__builtin_amdgcn_exp2f)
#define EXP2(x) __builtin_amdgcn_exp2f(x)
#else
#define EXP2(x) exp2f(x)
#endif
#else
#define EXP2(x) exp2f(x)
#endif

// q pre-scale: dh^-0.5 * log2(e), folded in fp32 BEFORE the single bf16
// rounding (scores exit QK^T already in log2 domain)
#define QSCALE 0.18033688011112f

// fp32 -> bf16 round-to-nearest-even (scalar path, used by GEMM kernels)
__device__ __forceinline__ unsigned short f2b(float f) {
    union { float fp; unsigned int u; } v; v.fp = f;
    unsigned int r = v.u + 0x7fffu + ((v.u >> 16) & 1u);
    return (unsigned short)(r >> 16);
}

// two fp32 -> packed 2x bf16 (RNE), lo = a, hi = b
__device__ __forceinline__ unsigned cvtpk(float a, float b) {
    unsigned r;
    asm("v_cvt_pk_bf16_f32 %0, %1, %2" : "=v"(r) : "v"(a), "v"(b));
    return r;
}

// XOR-swizzled LDS addressing for 64-col (128 B) bf16 rows: spreads the
// row-major column access (ds_read_b128 at fixed col, varying row) across
// 8 distinct 16B slots per 8-lane phase. Applied on BOTH write and read.
__device__ __forceinline__ void* swzp(const void* base, int row, int col) {
    return (void*)((const char*)base + ((row * 128 + col * 2) ^ ((row & 7) << 4)));
}

// ---------------------------------------------------------------------------
// Kernel 0: cast+transpose x [b][c][n] fp32 -> xb [b][n][c] bf16 (y<4),
// and cast qkv_w / proj_w fp32 -> bf16 (y==4). Single launch.
// ---------------------------------------------------------------------------
__global__ __launch_bounds__(256)
void cast_xw(const float* __restrict__ x, const float* __restrict__ qw,
             const float* __restrict__ pw, ushort* __restrict__ xb,
             ushort* __restrict__ qwb, ushort* __restrict__ pwb)
{
    const int t = threadIdx.x;
    if (blockIdx.y < 4) {
        __shared__ ushort T[64][72];   // [n][c]
        const int n0 = blockIdx.x * 64, c0 = blockIdx.y * 64, b = blockIdx.z;
        {   // read 64c x 64n, convert, transposed scatter into LDS
            const int c_l = t >> 2, ns = (t & 3) * 16;
            const float* src = &x[((b * Cin + c0 + c_l) << 10) + n0 + ns];
#pragma unroll
            for (int i = 0; i < 4; ++i) {
                const float4 v = *(const float4*)(src + 4 * i);
                T[ns + 4 * i + 0][c_l] = f2b(v.x);
                T[ns + 4 * i + 1][c_l] = f2b(v.y);
                T[ns + 4 * i + 2][c_l] = f2b(v.z);
                T[ns + 4 * i + 3][c_l] = f2b(v.w);
            }
        }
        __syncthreads();
        {   // write rows of c (contiguous) to xb
            const int n_l = t >> 2, cs = (t & 3) * 16;
            ushort* dst = &xb[((b << 10) + n0 + n_l) * Cin + c0 + cs];
            *(uint4*)dst       = *(const uint4*)&T[n_l][cs];
            *(uint4*)(dst + 8) = *(const uint4*)&T[n_l][cs + 8];
        }
    } else {
        // weights: 524288 floats total = 131072 float4; 256 blocks x 256 thr x 2
        const int nq4 = (1536 * Cin) / 4;
        const int base = ((blockIdx.z * 16 + blockIdx.x) * 256 + t) * 2;
#pragma unroll
        for (int g = 0; g < 2; ++g) {
            const int j = base + g;
            const float* src; ushort* dst; int jj;
            if (j < nq4) { src = qw; dst = qwb; jj = j; }
            else         { src = pw; dst = pwb; jj = j - nq4; }
            const float4 v = *(const float4*)(src + 4 * jj);
            ushort4 u; u.x = f2b(v.x); u.y = f2b(v.y); u.z = f2b(v.z); u.w = f2b(v.w);
            *(ushort4*)(dst + 4 * jj) = u;
        }
    }
}

// ---------------------------------------------------------------------------
// Kernel 1: QKV GEMM, bf16 MFMA 16x16x32, BK=64 (8 barriers instead of 16).
// Q/K o-tiles: C = W*X -> Ct [n][o] -> q/k [bh][n][64] (q pre-scaled QSCALE).
// V  o-tiles: swapped operands (C^T = X*W) -> vbuf TRANSPOSED [bh][d][n].
// LDS stride 72 ushorts: frag-read banks 4*(ln+quad) per 8-lane phase -> free.
// ---------------------------------------------------------------------------
__global__ __launch_bounds__(256)
void qkv_gemm(const ushort* __restrict__ xb, const ushort* __restrict__ wb,
              const float* __restrict__ bias,
              ushort* __restrict__ qb, ushort* __restrict__ kb, ushort* __restrict__ vb)
{
    __shared__ ushort lds[18432];        // 36.9 KB; staging + epilogue alias
    ushort* As = lds;                    // [128 o][72] (64 data + 8 pad)
    ushort* Bs = lds + 9216;             // [128 n][72]

    const int t = threadIdx.x;
    const int w = t >> 6, lane = t & 63, quad = lane >> 4, ln = lane & 15;
    const int n0 = blockIdx.x * 128;
    const int o0 = blockIdx.y * 128;
    const int b  = blockIdx.z;
    const int ow = (w & 1) * 64, nw = (w >> 1) * 64;
    const bool vpath = (o0 >= 1024);

    f4 acc[4][4];
#pragma unroll
    for (int i = 0; i < 4; ++i)
#pragma unroll
        for (int j = 0; j < 4; ++j) acc[i][j] = (f4){0.f, 0.f, 0.f, 0.f};

    const int rr = t >> 2, cc = (t & 3) * 16;
    for (int k0 = 0; k0 < Cin; k0 += 64) {
        __syncthreads();
#pragma unroll
        for (int p = 0; p < 2; ++p) {   // stage 128 rows x 64 k for A and B
            const int row = rr + p * 64;
            const ushort* sa = &wb[(o0 + row) * Cin + k0 + cc];
            *(uint4*)&As[row * 72 + cc]     = *(const uint4*)sa;
            *(uint4*)&As[row * 72 + cc + 8] = *(const uint4*)(sa + 8);
            const ushort* sb = &xb[((b << 10) + n0 + row) * Cin + k0 + cc];
            *(uint4*)&Bs[row * 72 + cc]     = *(const uint4*)sb;
            *(uint4*)&Bs[row * 72 + cc + 8] = *(const uint4*)(sb + 8);
        }
        __syncthreads();
#pragma unroll
        for (int sub = 0; sub < 2; ++sub) {
            short8 af[4], bf[4];
#pragma unroll
            for (int ot = 0; ot < 4; ++ot)
                af[ot] = *(const short8*)&As[(ow + ot * 16 + ln) * 72 + sub * 32 + quad * 8];
#pragma unroll
            for (int nt = 0; nt < 4; ++nt)
                bf[nt] = *(const short8*)&Bs[(nw + nt * 16 + ln) * 72 + sub * 32 + quad * 8];
            if (!vpath) {   // acc[ot][nt]: row = o, col = n
#pragma unroll
                for (int ot = 0; ot < 4; ++ot)
#pragma unroll
                    for (int nt = 0; nt < 4; ++nt)
                        acc[ot][nt] = __builtin_amdgcn_mfma_f32_16x16x32_bf16(
                            af[ot], bf[nt], acc[ot][nt], 0, 0, 0);
            } else {        // acc[nt][ot]: row = n, col = o (transposed C)
#pragma unroll
                for (int nt = 0; nt < 4; ++nt)
#pragma unroll
                    for (int ot = 0; ot < 4; ++ot)
                        acc[nt][ot] = __builtin_amdgcn_mfma_f32_16x16x32_bf16(
                            bf[nt], af[ot], acc[nt][ot], 0, 0, 0);
            }
        }
    }

    __syncthreads();                     // staging reads done; alias lds
    if (!vpath) {
        // ---- Q/K epilogue: Ct [n][136 o-stride], vectorized both ways ----
        ushort* Ct = lds;
        const float sc = (o0 < 512) ? QSCALE : 1.0f;
#pragma unroll
        for (int ot = 0; ot < 4; ++ot) {
            float bs[4];
#pragma unroll
            for (int rg = 0; rg < 4; ++rg)
                bs[rg] = bias[o0 + ow + ot * 16 + quad * 4 + rg];
#pragma unroll
            for (int nt = 0; nt < 4; ++nt) {
                ushort4 u;
                u.x = f2b((acc[ot][nt][0] + bs[0]) * sc);
                u.y = f2b((acc[ot][nt][1] + bs[1]) * sc);
                u.z = f2b((acc[ot][nt][2] + bs[2]) * sc);
                u.w = f2b((acc[ot][nt][3] + bs[3]) * sc);
                *(ushort4*)&Ct[(nw + nt * 16 + ln) * 136 + ow + ot * 16 + quad * 4] = u;
            }
        }
        __syncthreads();
        ushort* dst; int obase;
        if (o0 < 512) { dst = qb; obase = o0; }
        else          { dst = kb; obase = o0 - 512; }
        const int rn = t >> 1, hf = t & 1;
        const int bh = b * 8 + (obase >> 6) + hf;
        ushort* drow = &dst[(bh * Np + n0 + rn) << 6];
        const ushort* srow = &Ct[rn * 136 + hf * 64];
#pragma unroll
        for (int s = 0; s < 8; ++s)
            *(uint4*)(drow + s * 8) = *(const uint4*)(srow + s * 8);
    } else {
        // ---- V epilogue: Ct [o][136 n-stride] (rows = d), then [bh][d][n] ----
        ushort* Ct = lds;
#pragma unroll
        for (int ot = 0; ot < 4; ++ot) {
            const float bo = bias[o0 + ow + ot * 16 + ln];
#pragma unroll
            for (int nt = 0; nt < 4; ++nt) {
                ushort4 u;
                u.x = f2b(acc[nt][ot][0] + bo);
                u.y = f2b(acc[nt][ot][1] + bo);
                u.z = f2b(acc[nt][ot][2] + bo);
                u.w = f2b(acc[nt][ot][3] + bo);
                *(ushort4*)&Ct[(ow + ot * 16 + ln) * 136 + nw + nt * 16 + quad * 4] = u;
            }
        }
        __syncthreads();
        const int o_l = t >> 1, nh = (t & 1) * 64;
        const int bh = b * 8 + ((o0 - 1024) >> 6) + (o_l >> 6);
        ushort* drow = &vb[((size_t)bh << 16) + ((o_l & 63) << 10) + n0 + nh];
        const ushort* srow = &Ct[o_l * 136 + nh];
#pragma unroll
        for (int s = 0; s < 8; ++s)
            *(uint4*)(drow + s * 8) = *(const uint4*)(srow + s * 8);
    }
}

// ---------------------------------------------------------------------------
// Kernel 2: causal flash attention — LDS-staged K/V with async prefetch.
//  * 128 q-rows/block, 4 waves x 32 rows (2 q-frags): 32 MFMA per K-tile/wave,
//    half the block-steps and half the K/V staging traffic of the 64-row tile.
//  * K [k][64] and V^T [d][64] staged in LDS with T2 XOR swizzle (write AND
//    read swizzled) -> conflict-free ds_read_b128 fragment loads.
//  * T14 pipeline with RAW s_barrier + counted waits (__syncthreads would
//    drain vmcnt and kill the prefetch): tile kt+1 global loads are issued
//    before the visibility barrier and land during compute of tile kt.
//  * O^T = mfma(Vfrag, Pfrag): output col = lane's own q row -> softmax state
//    (m, l) applies per-lane, no cross-lane alpha/linv shuffles; epilogue is
//    8B vector stores.  P via wave-private LDS rows (stride 72, cheap).
//  * softmax in log2 domain, deferred rescale (THR=8), v_cvt_pk_bf16_f32.
// ---------------------------------------------------------------------------
__global__ __launch_bounds__(256, 4)
void attn(const ushort* __restrict__ qb, const ushort* __restrict__ kb,
          const ushort* __restrict__ vt, ushort* __restrict__ ob)
{
    __shared__ ushort Ks[64 * 64];   // [k][d], XOR-swizzled rows (8 KB)
    __shared__ ushort Vt[64 * 64];   // [d][k], XOR-swizzled rows (8 KB)
    __shared__ ushort Ps[128 * 72];  // [q_local][k], wave-private (18 KB)

    const int t    = threadIdx.x;
    const int w    = t >> 6;
    const int lane = t & 63;
    const int quad = lane >> 4;
    const int ln   = lane & 15;
    const int bh   = blockIdx.x & 127;
    const int qbk  = 7 - (int)(blockIdx.x >> 7);   // heavy blocks first
    const int q0   = qbk * 128;

    const int base0 = q0 + w * 32;       // first q row of frag0
    const int qhi0  = base0 + 15;        // last q row of frag0
    const int qhi1  = base0 + 31;        // last q row of frag1

    const ushort* __restrict__ kbh = kb + ((size_t)(bh * Np) << 6);
    const ushort* __restrict__ vbh = vt + ((size_t)bh << 16);

    const int srow = t >> 2, scol = (t & 3) * 16;   // staging: 64 rows x 64 col

    // ---- prologue: Q frags (kept in registers) + tile-0 prefetch
    short8 qa00, qa01, qa10, qa11;
    {
        const ushort* qr = &qb[((size_t)(bh * Np + base0 + ln) << 6) + quad * 8];
        qa00 = *(const short8*)qr;
        qa01 = *(const short8*)(qr + 32);
        qa10 = *(const short8*)(qr + 1024);        // +16 rows
        qa11 = *(const short8*)(qr + 1024 + 32);
    }
    uint4 kr0, kr1, vr0, vr1;                      // staging registers
    {
        const ushort* sk = &kbh[(srow << 6) + scol];
        kr0 = *(const uint4*)sk; kr1 = *(const uint4*)(sk + 8);
        const ushort* sv = &vbh[(srow << 10) + scol];
        vr0 = *(const uint4*)sv; vr1 = *(const uint4*)(sv + 8);
    }

    f4 o0[4], o1[4];
#pragma unroll
    for (int nt = 0; nt < 4; ++nt) { o0[nt] = (f4){0.f,0.f,0.f,0.f}; o1[nt] = (f4){0.f,0.f,0.f,0.f}; }
    float m0 = -INFINITY, l0 = 0.f;      // state for q = base0 + ln
    float m1 = -INFINITY, l1 = 0.f;      // state for q = base0 + 16 + ln

    const int prow0 = (w * 32 + ln) * 72;
    const int prow1 = prow0 + 16 * 72;

    const int ktmax = 2 * qbk + 1;       // block-level (all waves barrier)
    for (int kt = 0; kt <= ktmax; ++kt) {
        const int k0 = kt * 64;

        // ---- write staged tile (prefetched last iter; latency already hidden)
        asm volatile("s_waitcnt vmcnt(0)" ::: "memory");
        *(uint4*)swzp(Ks, srow, scol)     = kr0;
        *(uint4*)swzp(Ks, srow, scol + 8) = kr1;
        *(uint4*)swzp(Vt, srow, scol)     = vr0;
        *(uint4*)swzp(Vt, srow, scol + 8) = vr1;
        // ---- issue next tile's global loads; they fly across the barrier
        if (kt < ktmax) {
            const int nk0 = k0 + 64;
            const ushort* sk = &kbh[((nk0 + srow) << 6) + scol];
            kr0 = *(const uint4*)sk; kr1 = *(const uint4*)(sk + 8);
            const ushort* sv = &vbh[(srow << 10) + nk0 + scol];
            vr0 = *(const uint4*)sv; vr1 = *(const uint4*)(sv + 8);
        }
        asm volatile("s_waitcnt lgkmcnt(0)" ::: "memory");   // my ds_writes done
        __builtin_amdgcn_s_barrier();                        // tile visible

        if (k0 <= qhi1) {   // wave-uniform: this wave has unmasked keys
            // ---- S^T = K Q^T (shared K frags feed both q-frags), log2 domain
            f4 s0[4], s1[4];
#pragma unroll
            for (int mt = 0; mt < 4; ++mt) { s0[mt] = (f4){0.f,0.f,0.f,0.f}; s1[mt] = (f4){0.f,0.f,0.f,0.f}; }
            __builtin_amdgcn_s_setprio(1);
#pragma unroll
            for (int mt = 0; mt < 4; ++mt) {
                const int kmt = k0 + mt * 16;
                if (kmt > qhi1) continue;             // fully masked for wave
                const short8 ka0 = *(const short8*)swzp(Ks, mt * 16 + ln, quad * 8);
                const short8 ka1 = *(const short8*)swzp(Ks, mt * 16 + ln, 32 + quad * 8);
                s1[mt] = __builtin_amdgcn_mfma_f32_16x16x32_bf16(ka0, qa10, s1[mt], 0, 0, 0);
                s1[mt] = __builtin_amdgcn_mfma_f32_16x16x32_bf16(ka1, qa11, s1[mt], 0, 0, 0);
                if (kmt <= qhi0) {
                    s0[mt] = __builtin_amdgcn_mfma_f32_16x16x32_bf16(ka0, qa00, s0[mt], 0, 0, 0);
                    s0[mt] = __builtin_amdgcn_mfma_f32_16x16x32_bf16(ka1, qa01, s0[mt], 0, 0, 0);
                }
            }
            __builtin_amdgcn_s_setprio(0);

            // ---- causal mask (absolute indices), only near the diagonal
            if (k0 + 63 > base0) {
                const int q = base0 + ln;
#pragma unroll
                for (int mt = 0; mt < 4; ++mt)
#pragma unroll
                    for (int rg = 0; rg < 4; ++rg)
                        if (k0 + mt * 16 + quad * 4 + rg > q) s0[mt][rg] = -INFINITY;
            }
            if (k0 + 63 > base0 + 16) {
                const int q = base0 + 16 + ln;
#pragma unroll
                for (int mt = 0; mt < 4; ++mt)
#pragma unroll
                    for (int rg = 0; rg < 4; ++rg)
                        if (k0 + mt * 16 + quad * 4 + rg > q) s1[mt][rg] = -INFINITY;
            }

            // ---- online softmax frag0 (deferred rescale, THR=8, log2 domain)
            if (k0 <= qhi0) {
                float mx = s0[0][0];
#pragma unroll
                for (int mt = 0; mt < 4; ++mt)
#pragma unroll
                    for (int rg = 0; rg < 4; ++rg) mx = fmaxf(mx, s0[mt][rg]);
                mx = fmaxf(mx, __shfl_xor(mx, 16));
                mx = fmaxf(mx, __shfl_xor(mx, 32));
                if (!__all(mx <= m0 + 8.f)) {
                    const float mn = fmaxf(m0, mx);
                    const float al = EXP2(m0 - mn);   // first tile: exp2(-inf)=0
                    m0 = mn; l0 *= al;
#pragma unroll
                    for (int nt = 0; nt < 4; ++nt)
#pragma unroll
                        for (int rg = 0; rg < 4; ++rg) o0[nt][rg] *= al;
                }
                float rs = 0.f;
#pragma unroll
                for (int mt = 0; mt < 4; ++mt) {
                    const float p0 = EXP2(s0[mt][0] - m0);
                    const float p1 = EXP2(s0[mt][1] - m0);
                    const float p2 = EXP2(s0[mt][2] - m0);
                    const float p3 = EXP2(s0[mt][3] - m0);
                    rs += (p0 + p1) + (p2 + p3);
                    uint2 u; u.x = cvtpk(p0, p1); u.y = cvtpk(p2, p3);
                    *(uint2*)&Ps[prow0 + mt * 16 + quad * 4] = u;
                }
                rs += __shfl_xor(rs, 16);
                rs += __shfl_xor(rs, 32);
                l0 += rs;
            }
            // ---- frag1 (always has work when k0 <= qhi1)
            {
                float mx = s1[0][0];
#pragma unroll
                for (int mt = 0; mt < 4; ++mt)
#pragma unroll
                    for (int rg = 0; rg < 4; ++rg) mx = fmaxf(mx, s1[mt][rg]);
                mx = fmaxf(mx, __shfl_xor(mx, 16));
                mx = fmaxf(mx, __shfl_xor(mx, 32));
                if (!__all(mx <= m1 + 8.f)) {
                    const float mn = fmaxf(m1, mx);
                    const float al = EXP2(m1 - mn);
                    m1 = mn; l1 *= al;
#pragma unroll
                    for (int nt = 0; nt < 4; ++nt)
#pragma unroll
                        for (int rg = 0; rg < 4; ++rg) o1[nt][rg] *= al;
                }
                float rs = 0.f;
#pragma unroll
                for (int mt = 0; mt < 4; ++mt) {
                    const float p0 = EXP2(s1[mt][0] - m1);
                    const float p1 = EXP2(s1[mt][1] - m1);
                    const float p2 = EXP2(s1[mt][2] - m1);
                    const float p3 = EXP2(s1[mt][3] - m1);
                    rs += (p0 + p1) + (p2 + p3);
                    uint2 u; u.x = cvtpk(p0, p1); u.y = cvtpk(p2, p3);
                    *(uint2*)&Ps[prow1 + mt * 16 + quad * 4] = u;
                }
                rs += __shfl_xor(rs, 16);
                rs += __shfl_xor(rs, 32);
                l1 += rs;
            }

            // ---- O^T += V P : A = V frag (rows d), B = P frag (rows k).
#pragma unroll
            for (int ks = 0; ks < 2; ++ks) {
                const int kk = k0 + ks * 32;
                if (kk > qhi1) continue;              // both P halves all-zero
                const short8 pa1 = *(const short8*)&Ps[prow1 + ks * 32 + quad * 8];
                const short8 pa0 = *(const short8*)&Ps[prow0 + ks * 32 + quad * 8];
                const bool do0 = (kk <= qhi0);
                __builtin_amdgcn_s_setprio(1);
#pragma unroll
                for (int nt = 0; nt < 4; ++nt) {
                    const short8 vf = *(const short8*)swzp(Vt, nt * 16 + ln, ks * 32 + quad * 8);
                    o1[nt] = __builtin_amdgcn_mfma_f32_16x16x32_bf16(vf, pa1, o1[nt], 0, 0, 0);
                    if (do0)
                        o0[nt] = __builtin_amdgcn_mfma_f32_16x16x32_bf16(vf, pa0, o0[nt], 0, 0, 0);
                }
                __builtin_amdgcn_s_setprio(0);
            }
        }

        __builtin_amdgcn_s_barrier();    // all waves done reading this tile
    }

    // ---- epilogue: O^T rows d = nt*16+quad*4+rg, col q = own lane's row.
    const float li0 = 1.0f / l0;
    const float li1 = 1.0f / l1;
    ushort* orow0 = &ob[(size_t)(bh * Np + base0 + ln) << 6];
    ushort* orow1 = orow0 + 1024;        // +16 q rows
#pragma unroll
    for (int nt = 0; nt < 4; ++nt) {
        uint2 u;
        u.x = cvtpk(o0[nt][0] * li0, o0[nt][1] * li0);
        u.y = cvtpk(o0[nt][2] * li0, o0[nt][3] * li0);
        *(uint2*)(orow0 + nt * 16 + quad * 4) = u;
        uint2 v;
        v.x = cvtpk(o1[nt][0] * li1, o1[nt][1] * li1);
        v.y = cvtpk(o1[nt][2] * li1, o1[nt][3] * li1);
        *(uint2*)(orow1 + nt * 16 + quad * 4) = v;
    }
}

// ---------------------------------------------------------------------------
// Kernel 3: projection GEMM, bf16 MFMA, 64(o) x 128(n) tile, BK=64.
// Grid 512 blocks (2/CU). Wave w owns n strip [w*32, w*32+32).
// ---------------------------------------------------------------------------
__global__ __launch_bounds__(256)
void proj_gemm(const ushort* __restrict__ obuf, const ushort* __restrict__ pwb,
               const float* __restrict__ bias, float* __restrict__ out)
{
    __shared__ ushort As[64 * 72];    // pw [o][k]
    __shared__ ushort Bs[128 * 72];   // attn-out [n][k]

    const int t = threadIdx.x;
    const int w = t >> 6, lane = t & 63, quad = lane >> 4, ln = lane & 15;
    const int n0 = blockIdx.x * 128;
    const int o0 = blockIdx.y * 64;
    const int b  = blockIdx.z;
    const int nw = w * 32;

    f4 acc[4][2];
#pragma unroll
    for (int i = 0; i < 4; ++i)
#pragma unroll
        for (int j = 0; j < 2; ++j) acc[i][j] = (f4){0.f, 0.f, 0.f, 0.f};

    const int rr = t >> 2, cc = (t & 3) * 16;
    for (int k0 = 0; k0 < 512; k0 += 64) {
        __syncthreads();
        {   // A: 64 o-rows x 64 k; B: 128 n-rows x 64 k (one head per step)
            const ushort* sa = &pwb[(o0 + rr) * 512 + k0 + cc];
            *(uint4*)&As[rr * 72 + cc]     = *(const uint4*)sa;
            *(uint4*)&As[rr * 72 + cc + 8] = *(const uint4*)(sa + 8);
            const int head = k0 >> 6;
#pragma unroll
            for (int p = 0; p < 2; ++p) {
                const int row = rr + p * 64;
                const ushort* sb = &obuf[(((b * 8 + head) * Np + n0 + row) << 6) + cc];
                *(uint4*)&Bs[row * 72 + cc]     = *(const uint4*)sb;
                *(uint4*)&Bs[row * 72 + cc + 8] = *(const uint4*)(sb + 8);
            }
        }
        __syncthreads();
#pragma unroll
        for (int sub = 0; sub < 2; ++sub) {
            short8 af[4], bf[2];
#pragma unroll
            for (int ot = 0; ot < 4; ++ot)
                af[ot] = *(const short8*)&As[(ot * 16 + ln) * 72 + sub * 32 + quad * 8];
#pragma unroll
            for (int nt = 0; nt < 2; ++nt)
                bf[nt] = *(const short8*)&Bs[(nw + nt * 16 + ln) * 72 + sub * 32 + quad * 8];
#pragma unroll
            for (int ot = 0; ot < 4; ++ot)
#pragma unroll
                for (int nt = 0; nt < 2; ++nt)
                    acc[ot][nt] = __builtin_amdgcn_mfma_f32_16x16x32_bf16(
                        af[ot], bf[nt], acc[ot][nt], 0, 0, 0);
        }
    }

    // epilogue: direct fp32 stores (16-lane 64B segments), bias added
#pragma unroll
    for (int ot = 0; ot < 4; ++ot) {
#pragma unroll
        for (int rg = 0; rg < 4; ++rg) {
            const int oo = o0 + ot * 16 + quad * 4 + rg;
            const float pb = bias[oo];
            float* drow = &out[((b << 8) + oo) << 10];
#pragma unroll
            for (int nt = 0; nt < 2; ++nt)
                drow[n0 + nw + nt * 16 + ln] = acc[ot][nt][rg] + pb;
        }
    }
}

// ---------------------------------------------------------------------------
extern "C" void kernel_launch(void* const* d_in, const int* in_sizes, int n_in,
                              void* d_out, int out_size, void* d_ws, size_t ws_size,
                              hipStream_t stream)
{
    const float* x   = (const float*)d_in[0];   // [16,256,1024]
    const float* qw  = (const float*)d_in[1];   // [1536,256]
    const float* qbb = (const float*)d_in[2];   // [1536]
    const float* pw  = (const float*)d_in[3];   // [256,512]
    const float* pb  = (const float*)d_in[4];   // [256]
    float* out = (float*)d_out;                 // [16,256,1024]

    // workspace (all bf16): q/k [bh][n][64], v TRANSPOSED [bh][64][n],
    // attn-out [bh][n][64]; xb [b][n][c]; weights.
    const size_t per = (size_t)Bsz * 8 * Np * 64;
    ushort* qbuf = (ushort*)d_ws;
    ushort* kbuf = qbuf + per;
    ushort* vbuf = kbuf + per;
    ushort* obuf = vbuf + per;
    ushort* xb   = obuf + per;
    ushort* qwb  = xb + (size_t)Bsz * Np * Cin;
    ushort* pwb  = qwb + 1536 * Cin;

    cast_xw<<<dim3(16, 5, Bsz), 256, 0, stream>>>(x, qw, pw, xb, qwb, pwb);
    qkv_gemm<<<dim3(8, 12, Bsz), 256, 0, stream>>>(xb, qwb, qbb, qbuf, kbuf, vbuf);
    // 1024 blocks = 128 bh x 8 q-blocks of 128 rows; heavy (high qbk) first.
    // Same-bh blocks are 128 apart -> same XCD (128 % 8 == 0) -> K/V L2-local.
    attn<<<dim3(1024), 256, 0, stream>>>(qbuf, kbuf, vbuf, obuf);
    proj_gemm<<<dim3(8, 4, Bsz), 256, 0, stream>>>(obuf, pwb, pb, out);
}

// Round 3
// 152.274 us; speedup vs baseline: 1.3703x; 1.3703x over previous
//
#include <hip/hip_runtime.h>
#include <math.h>

// Problem constants: B=16, C_in=256, H=W=32 -> N=1024, qkv_out=1536,
// HEAD=8, dh=dv=64, V_DIM=512, OUT_CH=256.
static constexpr int Bsz = 16;
static constexpr int Np  = 1024;
static constexpr int Cin = 256;

typedef __attribute__((ext_vector_type(8))) short short8;  // 8 bf16 = 4 VGPR
typedef __attribute__((ext_vector_type(4))) float f4;      // mfma acc

// v_exp_f32 computes 2^x natively; use it without the log2e multiply.
#if defined(__has_builtin)
#if __has_builtin(__builtin_amdgcn_exp2f)
#define EXP2(x) __builtin_amdgcn_exp2f(x)
#else
#define EXP2(x) exp2f(x)
#endif
#else
#define EXP2(x) exp2f(x)
#endif

// q pre-scale: dh^-0.5 * log2(e), folded in fp32 BEFORE the single bf16
// rounding (scores exit QK^T already in log2 domain)
#define QSCALE 0.18033688011112f

// fp32 -> bf16 round-to-nearest-even (scalar path, used by GEMM kernels)
__device__ __forceinline__ unsigned short f2b(float f) {
    union { float fp; unsigned int u; } v; v.fp = f;
    unsigned int r = v.u + 0x7fffu + ((v.u >> 16) & 1u);
    return (unsigned short)(r >> 16);
}

// two fp32 -> packed 2x bf16 (RNE), lo = a, hi = b
__device__ __forceinline__ unsigned cvtpk(float a, float b) {
    unsigned r;
    asm("v_cvt_pk_bf16_f32 %0, %1, %2" : "=v"(r) : "v"(a), "v"(b));
    return r;
}

// XOR-swizzled LDS addressing for 64-col (128 B) bf16 rows. Measured (r1 vs
// r2 counters): this staging+read pattern is exactly conflict-free, while the
// stride-72 pad layout cost 4.36M conflict cycles. Applied on write AND read.
__device__ __forceinline__ void* swzp(const void* base, int row, int col) {
    return (void*)((const char*)base + ((row * 128 + col * 2) ^ ((row & 7) << 4)));
}

// ---------------------------------------------------------------------------
// Kernel 0: cast+transpose x [b][c][n] fp32 -> xb [b][n][c] bf16 (y<4),
// and cast qkv_w / proj_w fp32 -> bf16 (y==4). Single launch.
// ---------------------------------------------------------------------------
__global__ __launch_bounds__(256)
void cast_xw(const float* __restrict__ x, const float* __restrict__ qw,
             const float* __restrict__ pw, ushort* __restrict__ xb,
             ushort* __restrict__ qwb, ushort* __restrict__ pwb)
{
    const int t = threadIdx.x;
    if (blockIdx.y < 4) {
        __shared__ ushort T[64][72];   // [n][c]
        const int n0 = blockIdx.x * 64, c0 = blockIdx.y * 64, b = blockIdx.z;
        {   // read 64c x 64n, convert, transposed scatter into LDS
            const int c_l = t >> 2, ns = (t & 3) * 16;
            const float* src = &x[((b * Cin + c0 + c_l) << 10) + n0 + ns];
#pragma unroll
            for (int i = 0; i < 4; ++i) {
                const float4 v = *(const float4*)(src + 4 * i);
                T[ns + 4 * i + 0][c_l] = f2b(v.x);
                T[ns + 4 * i + 1][c_l] = f2b(v.y);
                T[ns + 4 * i + 2][c_l] = f2b(v.z);
                T[ns + 4 * i + 3][c_l] = f2b(v.w);
            }
        }
        __syncthreads();
        {   // write rows of c (contiguous) to xb
            const int n_l = t >> 2, cs = (t & 3) * 16;
            ushort* dst = &xb[((b << 10) + n0 + n_l) * Cin + c0 + cs];
            *(uint4*)dst       = *(const uint4*)&T[n_l][cs];
            *(uint4*)(dst + 8) = *(const uint4*)&T[n_l][cs + 8];
        }
    } else {
        // weights: 524288 floats total = 131072 float4; 256 blocks x 256 thr x 2
        const int nq4 = (1536 * Cin) / 4;
        const int base = ((blockIdx.z * 16 + blockIdx.x) * 256 + t) * 2;
#pragma unroll
        for (int g = 0; g < 2; ++g) {
            const int j = base + g;
            const float* src; ushort* dst; int jj;
            if (j < nq4) { src = qw; dst = qwb; jj = j; }
            else         { src = pw; dst = pwb; jj = j - nq4; }
            const float4 v = *(const float4*)(src + 4 * jj);
            ushort4 u; u.x = f2b(v.x); u.y = f2b(v.y); u.z = f2b(v.z); u.w = f2b(v.w);
            *(ushort4*)(dst + 4 * jj) = u;
        }
    }
}

// ---------------------------------------------------------------------------
// Kernel 1: QKV GEMM, bf16 MFMA 16x16x32, BK=64 (8 barriers instead of 16).
// Q/K o-tiles: C = W*X -> Ct [n][o] -> q/k [bh][n][64] (q pre-scaled QSCALE).
// V  o-tiles: swapped operands (C^T = X*W) -> vbuf TRANSPOSED [bh][d][n].
// LDS stride 72 ushorts: frag-read banks 4*(ln+quad) per 8-lane phase -> free.
// ---------------------------------------------------------------------------
__global__ __launch_bounds__(256)
void qkv_gemm(const ushort* __restrict__ xb, const ushort* __restrict__ wb,
              const float* __restrict__ bias,
              ushort* __restrict__ qb, ushort* __restrict__ kb, ushort* __restrict__ vb)
{
    __shared__ ushort lds[18432];        // 36.9 KB; staging + epilogue alias
    ushort* As = lds;                    // [128 o][72] (64 data + 8 pad)
    ushort* Bs = lds + 9216;             // [128 n][72]

    const int t = threadIdx.x;
    const int w = t >> 6, lane = t & 63, quad = lane >> 4, ln = lane & 15;
    const int n0 = blockIdx.x * 128;
    const int o0 = blockIdx.y * 128;
    const int b  = blockIdx.z;
    const int ow = (w & 1) * 64, nw = (w >> 1) * 64;
    const bool vpath = (o0 >= 1024);

    f4 acc[4][4];
#pragma unroll
    for (int i = 0; i < 4; ++i)
#pragma unroll
        for (int j = 0; j < 4; ++j) acc[i][j] = (f4){0.f, 0.f, 0.f, 0.f};

    const int rr = t >> 2, cc = (t & 3) * 16;
    for (int k0 = 0; k0 < Cin; k0 += 64) {
        __syncthreads();
#pragma unroll
        for (int p = 0; p < 2; ++p) {   // stage 128 rows x 64 k for A and B
            const int row = rr + p * 64;
            const ushort* sa = &wb[(o0 + row) * Cin + k0 + cc];
            *(uint4*)&As[row * 72 + cc]     = *(const uint4*)sa;
            *(uint4*)&As[row * 72 + cc + 8] = *(const uint4*)(sa + 8);
            const ushort* sb = &xb[((b << 10) + n0 + row) * Cin + k0 + cc];
            *(uint4*)&Bs[row * 72 + cc]     = *(const uint4*)sb;
            *(uint4*)&Bs[row * 72 + cc + 8] = *(const uint4*)(sb + 8);
        }
        __syncthreads();
#pragma unroll
        for (int sub = 0; sub < 2; ++sub) {
            short8 af[4], bf[4];
#pragma unroll
            for (int ot = 0; ot < 4; ++ot)
                af[ot] = *(const short8*)&As[(ow + ot * 16 + ln) * 72 + sub * 32 + quad * 8];
#pragma unroll
            for (int nt = 0; nt < 4; ++nt)
                bf[nt] = *(const short8*)&Bs[(nw + nt * 16 + ln) * 72 + sub * 32 + quad * 8];
            if (!vpath) {   // acc[ot][nt]: row = o, col = n
#pragma unroll
                for (int ot = 0; ot < 4; ++ot)
#pragma unroll
                    for (int nt = 0; nt < 4; ++nt)
                        acc[ot][nt] = __builtin_amdgcn_mfma_f32_16x16x32_bf16(
                            af[ot], bf[nt], acc[ot][nt], 0, 0, 0);
            } else {        // acc[nt][ot]: row = n, col = o (transposed C)
#pragma unroll
                for (int nt = 0; nt < 4; ++nt)
#pragma unroll
                    for (int ot = 0; ot < 4; ++ot)
                        acc[nt][ot] = __builtin_amdgcn_mfma_f32_16x16x32_bf16(
                            bf[nt], af[ot], acc[nt][ot], 0, 0, 0);
            }
        }
    }

    __syncthreads();                     // staging reads done; alias lds
    if (!vpath) {
        // ---- Q/K epilogue: Ct [n][136 o-stride], vectorized both ways ----
        ushort* Ct = lds;
        const float sc = (o0 < 512) ? QSCALE : 1.0f;
#pragma unroll
        for (int ot = 0; ot < 4; ++ot) {
            float bs[4];
#pragma unroll
            for (int rg = 0; rg < 4; ++rg)
                bs[rg] = bias[o0 + ow + ot * 16 + quad * 4 + rg];
#pragma unroll
            for (int nt = 0; nt < 4; ++nt) {
                ushort4 u;
                u.x = f2b((acc[ot][nt][0] + bs[0]) * sc);
                u.y = f2b((acc[ot][nt][1] + bs[1]) * sc);
                u.z = f2b((acc[ot][nt][2] + bs[2]) * sc);
                u.w = f2b((acc[ot][nt][3] + bs[3]) * sc);
                *(ushort4*)&Ct[(nw + nt * 16 + ln) * 136 + ow + ot * 16 + quad * 4] = u;
            }
        }
        __syncthreads();
        ushort* dst; int obase;
        if (o0 < 512) { dst = qb; obase = o0; }
        else          { dst = kb; obase = o0 - 512; }
        const int rn = t >> 1, hf = t & 1;
        const int bh = b * 8 + (obase >> 6) + hf;
        ushort* drow = &dst[(bh * Np + n0 + rn) << 6];
        const ushort* srow = &Ct[rn * 136 + hf * 64];
#pragma unroll
        for (int s = 0; s < 8; ++s)
            *(uint4*)(drow + s * 8) = *(const uint4*)(srow + s * 8);
    } else {
        // ---- V epilogue: Ct [o][136 n-stride] (rows = d), then [bh][d][n] ----
        ushort* Ct = lds;
#pragma unroll
        for (int ot = 0; ot < 4; ++ot) {
            const float bo = bias[o0 + ow + ot * 16 + ln];
#pragma unroll
            for (int nt = 0; nt < 4; ++nt) {
                ushort4 u;
                u.x = f2b(acc[nt][ot][0] + bo);
                u.y = f2b(acc[nt][ot][1] + bo);
                u.z = f2b(acc[nt][ot][2] + bo);
                u.w = f2b(acc[nt][ot][3] + bo);
                *(ushort4*)&Ct[(ow + ot * 16 + ln) * 136 + nw + nt * 16 + quad * 4] = u;
            }
        }
        __syncthreads();
        const int o_l = t >> 1, nh = (t & 1) * 64;
        const int bh = b * 8 + ((o0 - 1024) >> 6) + (o_l >> 6);
        ushort* drow = &vb[((size_t)bh << 16) + ((o_l & 63) << 10) + n0 + nh];
        const ushort* srow = &Ct[o_l * 136 + nh];
#pragma unroll
        for (int s = 0; s < 8; ++s)
            *(uint4*)(drow + s * 8) = *(const uint4*)(srow + s * 8);
    }
}

// ---------------------------------------------------------------------------
// Kernel 2: causal flash attention — round-0 skeleton + validated grafts.
//  * 64 q-rows/block, 4 waves (wave w owns q rows w*16..w*16+15), 2048 blocks,
//    plain __syncthreads staging (best measured structure: 55.5 us).
//  * K [k][64] and V^T [d][64] staged with XOR swizzle on write AND read
//    (measured conflict-free in r1/r2; stride-72 cost 4.36M conflict cycles).
//  * O^T = mfma(Vfrag, Pfrag): output col = lane's own q row -> softmax state
//    (m, l) per-lane, no alpha/linv shuffles; 8B vector epilogue stores.
//  * deferred rescale (THR=8, log2 domain) + v_cvt_pk_bf16_f32 P-packing.
//  * LDS 25.6 KB (Q staged into Ps alias) -> 6 blocks/CU (was 4).
// ---------------------------------------------------------------------------
__global__ __launch_bounds__(256, 6)
void attn(const ushort* __restrict__ qb, const ushort* __restrict__ kb,
          const ushort* __restrict__ vt, ushort* __restrict__ ob)
{
    __shared__ ushort Ks[64 * 64];   // [k][d], XOR-swizzled (8 KB)
    __shared__ ushort Vt[64 * 64];   // [d][k], XOR-swizzled (8 KB)
    __shared__ ushort Ps[64 * 72];   // [q][k] wave-private; Q-alias in prologue

    const int t    = threadIdx.x;
    const int w    = t >> 6;
    const int lane = t & 63;
    const int quad = lane >> 4;
    const int ln   = lane & 15;
    const int bh   = blockIdx.x & 127;
    const int qt   = 15 - (int)(blockIdx.x >> 7);   // heavy blocks first
    const int q0   = qt * 64;

    const ushort* __restrict__ kbh = kb + ((size_t)(bh * Np) << 6);
    const ushort* __restrict__ vbh = vt + ((size_t)bh << 16);

    {   // stage Q tile into Ps alias (dead after frag reads below)
        const int r = t & 63, seg = t >> 6;
        const ushort* src = &qb[((size_t)(bh * Np + q0 + r) << 6) + seg * 16];
        *(uint4*)&Ps[r * 72 + seg * 16]     = *(const uint4*)src;
        *(uint4*)&Ps[r * 72 + seg * 16 + 8] = *(const uint4*)(src + 8);
    }
    __syncthreads();

    const short8 qa0 = *(const short8*)&Ps[(w * 16 + ln) * 72 + quad * 8];
    const short8 qa1 = *(const short8*)&Ps[(w * 16 + ln) * 72 + 32 + quad * 8];

    f4 o_[4];
#pragma unroll
    for (int nt = 0; nt < 4; ++nt) o_[nt] = (f4){0.f, 0.f, 0.f, 0.f};
    float m = -INFINITY, l = 0.f;        // state for q = qrow (per lane)

    const int srow = t >> 2, scol = (t & 3) * 16;   // staging: 64 rows x 64 col
    const int prow = (w * 16 + ln) * 72;
    const int qrow = q0 + w * 16 + ln;   // lane's q row (absolute)

    for (int kt = 0; kt <= qt; ++kt) {
        const int k0 = kt * 64;
        __syncthreads();
        {   // stage K [k][d] and Vt [d][k], swizzled writes (conflict-free)
            const ushort* sk = &kbh[((k0 + srow) << 6) + scol];
            *(uint4*)swzp(Ks, srow, scol)     = *(const uint4*)sk;
            *(uint4*)swzp(Ks, srow, scol + 8) = *(const uint4*)(sk + 8);
            const ushort* sv = &vbh[(srow << 10) + k0 + scol];
            *(uint4*)swzp(Vt, srow, scol)     = *(const uint4*)sv;
            *(uint4*)swzp(Vt, srow, scol + 8) = *(const uint4*)(sv + 8);
        }
        __syncthreads();

        const bool diag = (kt == qt);

        // ---- S^T = K Q^T : rows k = mt*16+quad*4+rg, col q = ln (log2 dom.)
        f4 st[4];
#pragma unroll
        for (int mt = 0; mt < 4; ++mt) st[mt] = (f4){0.f, 0.f, 0.f, 0.f};
#pragma unroll
        for (int mt = 0; mt < 4; ++mt) {
            if (diag && mt > w) continue;   // fully-masked tile (wave-uniform)
            const short8 ka0 = *(const short8*)swzp(Ks, mt * 16 + ln, quad * 8);
            const short8 ka1 = *(const short8*)swzp(Ks, mt * 16 + ln, 32 + quad * 8);
            st[mt] = __builtin_amdgcn_mfma_f32_16x16x32_bf16(ka0, qa0, st[mt], 0, 0, 0);
            st[mt] = __builtin_amdgcn_mfma_f32_16x16x32_bf16(ka1, qa1, st[mt], 0, 0, 0);
        }

        if (diag) {   // mask k > q
#pragma unroll
            for (int mt = 0; mt < 4; ++mt)
#pragma unroll
                for (int rg = 0; rg < 4; ++rg)
                    if (k0 + mt * 16 + quad * 4 + rg > qrow) st[mt][rg] = -INFINITY;
        }

        // ---- online softmax (log2 domain), deferred rescale THR=8
        float mx = st[0][0];
#pragma unroll
        for (int mt = 0; mt < 4; ++mt)
#pragma unroll
            for (int rg = 0; rg < 4; ++rg) mx = fmaxf(mx, st[mt][rg]);
        mx = fmaxf(mx, __shfl_xor(mx, 16));
        mx = fmaxf(mx, __shfl_xor(mx, 32));

        if (!__all(mx <= m + 8.f)) {
            const float mn = fmaxf(m, mx);
            const float al = EXP2(m - mn);   // first tile: exp2(-inf) = 0
            m = mn; l *= al;
#pragma unroll
            for (int nt = 0; nt < 4; ++nt)
#pragma unroll
                for (int rg = 0; rg < 4; ++rg) o_[nt][rg] *= al;   // col = own q
        }

        float rs = 0.f;
#pragma unroll
        for (int mt = 0; mt < 4; ++mt) {
            const float p0 = EXP2(st[mt][0] - m);
            const float p1 = EXP2(st[mt][1] - m);
            const float p2 = EXP2(st[mt][2] - m);
            const float p3 = EXP2(st[mt][3] - m);
            rs += (p0 + p1) + (p2 + p3);
            uint2 u; u.x = cvtpk(p0, p1); u.y = cvtpk(p2, p3);
            *(uint2*)&Ps[prow + mt * 16 + quad * 4] = u;
        }
        rs += __shfl_xor(rs, 16);
        rs += __shfl_xor(rs, 32);
        l += rs;

        // ---- O^T += V P : A = V frag (rows d), B = P frag (rows q, own wave)
#pragma unroll
        for (int ks = 0; ks < 2; ++ks) {
            if (diag && w * 16 + 15 < ks * 32) continue;   // zero P half
            const short8 pa = *(const short8*)&Ps[prow + ks * 32 + quad * 8];
#pragma unroll
            for (int nt = 0; nt < 4; ++nt) {
                const short8 vf = *(const short8*)swzp(Vt, nt * 16 + ln, ks * 32 + quad * 8);
                o_[nt] = __builtin_amdgcn_mfma_f32_16x16x32_bf16(vf, pa, o_[nt], 0, 0, 0);
            }
        }
    }

    // ---- epilogue: O^T rows d = nt*16+quad*4+rg, col q = own lane's row
    const float li = 1.0f / l;
    ushort* orow = &ob[(size_t)(bh * Np + qrow) << 6];
#pragma unroll
    for (int nt = 0; nt < 4; ++nt) {
        uint2 u;
        u.x = cvtpk(o_[nt][0] * li, o_[nt][1] * li);
        u.y = cvtpk(o_[nt][2] * li, o_[nt][3] * li);
        *(uint2*)(orow + nt * 16 + quad * 4) = u;
    }
}

// ---------------------------------------------------------------------------
// Kernel 3: projection GEMM, bf16 MFMA, 64(o) x 128(n) tile, BK=64.
// Grid 512 blocks (2/CU). Wave w owns n strip [w*32, w*32+32).
// ---------------------------------------------------------------------------
__global__ __launch_bounds__(256)
void proj_gemm(const ushort* __restrict__ obuf, const ushort* __restrict__ pwb,
               const float* __restrict__ bias, float* __restrict__ out)
{
    __shared__ ushort As[64 * 72];    // pw [o][k]
    __shared__ ushort Bs[128 * 72];   // attn-out [n][k]

    const int t = threadIdx.x;
    const int w = t >> 6, lane = t & 63, quad = lane >> 4, ln = lane & 15;
    const int n0 = blockIdx.x * 128;
    const int o0 = blockIdx.y * 64;
    const int b  = blockIdx.z;
    const int nw = w * 32;

    f4 acc[4][2];
#pragma unroll
    for (int i = 0; i < 4; ++i)
#pragma unroll
        for (int j = 0; j < 2; ++j) acc[i][j] = (f4){0.f, 0.f, 0.f, 0.f};

    const int rr = t >> 2, cc = (t & 3) * 16;
    for (int k0 = 0; k0 < 512; k0 += 64) {
        __syncthreads();
        {   // A: 64 o-rows x 64 k; B: 128 n-rows x 64 k (one head per step)
            const ushort* sa = &pwb[(o0 + rr) * 512 + k0 + cc];
            *(uint4*)&As[rr * 72 + cc]     = *(const uint4*)sa;
            *(uint4*)&As[rr * 72 + cc + 8] = *(const uint4*)(sa + 8);
            const int head = k0 >> 6;
#pragma unroll
            for (int p = 0; p < 2; ++p) {
                const int row = rr + p * 64;
                const ushort* sb = &obuf[(((b * 8 + head) * Np + n0 + row) << 6) + cc];
                *(uint4*)&Bs[row * 72 + cc]     = *(const uint4*)sb;
                *(uint4*)&Bs[row * 72 + cc + 8] = *(const uint4*)(sb + 8);
            }
        }
        __syncthreads();
#pragma unroll
        for (int sub = 0; sub < 2; ++sub) {
            short8 af[4], bf[2];
#pragma unroll
            for (int ot = 0; ot < 4; ++ot)
                af[ot] = *(const short8*)&As[(ot * 16 + ln) * 72 + sub * 32 + quad * 8];
#pragma unroll
            for (int nt = 0; nt < 2; ++nt)
                bf[nt] = *(const short8*)&Bs[(nw + nt * 16 + ln) * 72 + sub * 32 + quad * 8];
#pragma unroll
            for (int ot = 0; ot < 4; ++ot)
#pragma unroll
                for (int nt = 0; nt < 2; ++nt)
                    acc[ot][nt] = __builtin_amdgcn_mfma_f32_16x16x32_bf16(
                        af[ot], bf[nt], acc[ot][nt], 0, 0, 0);
        }
    }

    // epilogue: direct fp32 stores (16-lane 64B segments), bias added
#pragma unroll
    for (int ot = 0; ot < 4; ++ot) {
#pragma unroll
        for (int rg = 0; rg < 4; ++rg) {
            const int oo = o0 + ot * 16 + quad * 4 + rg;
            const float pb = bias[oo];
            float* drow = &out[((b << 8) + oo) << 10];
#pragma unroll
            for (int nt = 0; nt < 2; ++nt)
                drow[n0 + nw + nt * 16 + ln] = acc[ot][nt][rg] + pb;
        }
    }
}

// ---------------------------------------------------------------------------
extern "C" void kernel_launch(void* const* d_in, const int* in_sizes, int n_in,
                              void* d_out, int out_size, void* d_ws, size_t ws_size,
                              hipStream_t stream)
{
    const float* x   = (const float*)d_in[0];   // [16,256,1024]
    const float* qw  = (const float*)d_in[1];   // [1536,256]
    const float* qbb = (const float*)d_in[2];   // [1536]
    const float* pw  = (const float*)d_in[3];   // [256,512]
    const float* pb  = (const float*)d_in[4];   // [256]
    float* out = (float*)d_out;                 // [16,256,1024]

    // workspace (all bf16): q/k [bh][n][64], v TRANSPOSED [bh][64][n],
    // attn-out [bh][n][64]; xb [b][n][c]; weights.
    const size_t per = (size_t)Bsz * 8 * Np * 64;
    ushort* qbuf = (ushort*)d_ws;
    ushort* kbuf = qbuf + per;
    ushort* vbuf = kbuf + per;
    ushort* obuf = vbuf + per;
    ushort* xb   = obuf + per;
    ushort* qwb  = xb + (size_t)Bsz * Np * Cin;
    ushort* pwb  = qwb + 1536 * Cin;

    cast_xw<<<dim3(16, 5, Bsz), 256, 0, stream>>>(x, qw, pw, xb, qwb, pwb);
    qkv_gemm<<<dim3(8, 12, Bsz), 256, 0, stream>>>(xb, qwb, qbb, qbuf, kbuf, vbuf);
    // 2048 blocks = 128 bh x 16 q-tiles of 64 rows; heavy (high qt) first.
    attn<<<dim3(128 * 16), 256, 0, stream>>>(qbuf, kbuf, vbuf, obuf);
    proj_gemm<<<dim3(8, 4, Bsz), 256, 0, stream>>>(obuf, pwb, pb, out);
}

// Round 5
// 150.510 us; speedup vs baseline: 1.3864x; 1.0117x over previous
//
#include <hip/hip_runtime.h>
#include <math.h>

// Problem constants: B=16, C_in=256, H=W=32 -> N=1024, qkv_out=1536,
// HEAD=8, dh=dv=64, V_DIM=512, OUT_CH=256.
static constexpr int Bsz = 16;
static constexpr int Np  = 1024;
static constexpr int Cin = 256;

typedef __attribute__((ext_vector_type(8))) short short8;  // 8 bf16 = 4 VGPR
typedef __attribute__((ext_vector_type(4))) float f4;      // mfma acc

// v_exp_f32 computes 2^x natively; use it without the log2e multiply.
#if defined(__has_builtin)
#if __has_builtin(__builtin_amdgcn_exp2f)
#define EXP2(x) __builtin_amdgcn_exp2f(x)
#else
#define EXP2(x) exp2f(x)
#endif
#else
#define EXP2(x) exp2f(x)
#endif

// q pre-scale: dh^-0.5 * log2(e), folded in fp32 BEFORE the single bf16
// rounding (scores exit QK^T already in log2 domain)
#define QSCALE 0.18033688011112f

// fp32 -> bf16 round-to-nearest-even (scalar path, used by GEMM kernels)
__device__ __forceinline__ unsigned short f2b(float f) {
    union { float fp; unsigned int u; } v; v.fp = f;
    unsigned int r = v.u + 0x7fffu + ((v.u >> 16) & 1u);
    return (unsigned short)(r >> 16);
}

// two fp32 -> packed 2x bf16 (RNE), lo = a, hi = b
__device__ __forceinline__ unsigned cvtpk(float a, float b) {
    unsigned r;
    asm("v_cvt_pk_bf16_f32 %0, %1, %2" : "=v"(r) : "v"(a), "v"(b));
    return r;
}

// XOR-swizzled LDS read addressing for 64-col (128 B) bf16 rows (stride 64,
// NO pad). LDS[row][c16] holds global col16 (c16 ^ (row&7)) -> reading col j
// at c16 = j ^ (row&7) returns the logical value. Measured conflict-free
// (r1 vs r2 counters). Write side is LINEAR (global_load_lds) with the same
// XOR folded into the per-lane global SOURCE address (m201 pattern).
__device__ __forceinline__ void* swzp(const void* base, int row, int col) {
    return (void*)((const char*)base + ((row * 128 + col * 2) ^ ((row & 7) << 4)));
}

// async global->LDS, 16 B per lane; dest = wave-uniform base + lane*16.
__device__ __forceinline__ void gl16(const ushort* g, ushort* l) {
    __builtin_amdgcn_global_load_lds(
        (const __attribute__((address_space(1))) unsigned int*)g,
        (__attribute__((address_space(3))) unsigned int*)l, 16, 0, 0);
}

// ---------------------------------------------------------------------------
// Kernel 0: cast+transpose x [b][c][n] fp32 -> xb [b][n][c] bf16 (y<4),
// and cast qkv_w / proj_w fp32 -> bf16 (y==4). Single launch.
// ---------------------------------------------------------------------------
__global__ __launch_bounds__(256)
void cast_xw(const float* __restrict__ x, const float* __restrict__ qw,
             const float* __restrict__ pw, ushort* __restrict__ xb,
             ushort* __restrict__ qwb, ushort* __restrict__ pwb)
{
    const int t = threadIdx.x;
    if (blockIdx.y < 4) {
        __shared__ ushort T[64][72];   // [n][c]
        const int n0 = blockIdx.x * 64, c0 = blockIdx.y * 64, b = blockIdx.z;
        {   // read 64c x 64n, convert, transposed scatter into LDS
            const int c_l = t >> 2, ns = (t & 3) * 16;
            const float* src = &x[((b * Cin + c0 + c_l) << 10) + n0 + ns];
#pragma unroll
            for (int i = 0; i < 4; ++i) {
                const float4 v = *(const float4*)(src + 4 * i);
                T[ns + 4 * i + 0][c_l] = f2b(v.x);
                T[ns + 4 * i + 1][c_l] = f2b(v.y);
                T[ns + 4 * i + 2][c_l] = f2b(v.z);
                T[ns + 4 * i + 3][c_l] = f2b(v.w);
            }
        }
        __syncthreads();
        {   // write rows of c (contiguous) to xb
            const int n_l = t >> 2, cs = (t & 3) * 16;
            ushort* dst = &xb[((b << 10) + n0 + n_l) * Cin + c0 + cs];
            *(uint4*)dst       = *(const uint4*)&T[n_l][cs];
            *(uint4*)(dst + 8) = *(const uint4*)&T[n_l][cs + 8];
        }
    } else {
        // weights: 524288 floats total = 131072 float4; 256 blocks x 256 thr x 2
        const int nq4 = (1536 * Cin) / 4;
        const int base = ((blockIdx.z * 16 + blockIdx.x) * 256 + t) * 2;
#pragma unroll
        for (int g = 0; g < 2; ++g) {
            const int j = base + g;
            const float* src; ushort* dst; int jj;
            if (j < nq4) { src = qw; dst = qwb; jj = j; }
            else         { src = pw; dst = pwb; jj = j - nq4; }
            const float4 v = *(const float4*)(src + 4 * jj);
            ushort4 u; u.x = f2b(v.x); u.y = f2b(v.y); u.z = f2b(v.z); u.w = f2b(v.w);
            *(ushort4*)(dst + 4 * jj) = u;
        }
    }
}

// ---------------------------------------------------------------------------
// Kernel 1: QKV GEMM, bf16 MFMA 16x16x32, BK=64, m97-style staging:
// global_load_lds x16B into LINEAR stride-64 LDS, XOR swizzle folded into the
// per-lane global source; fragment reads via swzp (conflict-free).
// Q/K o-tiles: C = W*X -> Ct [n][o] -> q/k [bh][n][64] (q pre-scaled QSCALE).
// V  o-tiles: swapped operands (C^T = X*W) -> vbuf TRANSPOSED [bh][d][n].
// ---------------------------------------------------------------------------
__global__ __launch_bounds__(256)
void qkv_gemm(const ushort* __restrict__ xb, const ushort* __restrict__ wb,
              const float* __restrict__ bias,
              ushort* __restrict__ qb, ushort* __restrict__ kb, ushort* __restrict__ vb)
{
    __shared__ ushort lds[17408];        // 34.8 KB; staging (32 KB) + Ct alias
    ushort* As = lds;                    // [128 o][64]  (linear, swizzled data)
    ushort* Bs = lds + 8192;             // [128 n][64]

    const int t = threadIdx.x;
    const int w = t >> 6, lane = t & 63, quad = lane >> 4, ln = lane & 15;
    const int n0 = blockIdx.x * 128;
    const int o0 = blockIdx.y * 128;
    const int b  = blockIdx.z;
    const int ow = (w & 1) * 64, nw = (w >> 1) * 64;
    const bool vpath = (o0 >= 1024);

    // per-lane staging source: lane covers LDS (row8 = lane>>3, c16 = lane&7);
    // global col16 = c16 ^ row8 (inverse swizzle), in ushorts:
    const int r8  = lane >> 3;
    const int c16 = ((lane & 7) ^ r8) << 3;

    f4 acc[4][4];
#pragma unroll
    for (int i = 0; i < 4; ++i)
#pragma unroll
        for (int j = 0; j < 4; ++j) acc[i][j] = (f4){0.f, 0.f, 0.f, 0.f};

    for (int k0 = 0; k0 < Cin; k0 += 64) {
        __syncthreads();
#pragma unroll
        for (int j = 0; j < 4; ++j) {    // wave w stages rows [w*32, w*32+32)
            const int row = w * 32 + j * 8 + r8;
            gl16(&wb[(o0 + row) * Cin + k0 + c16],              &As[(w * 32 + j * 8) * 64]);
            gl16(&xb[((b << 10) + n0 + row) * Cin + k0 + c16],  &Bs[(w * 32 + j * 8) * 64]);
        }
        __syncthreads();                 // drains vmcnt -> tile visible
#pragma unroll
        for (int sub = 0; sub < 2; ++sub) {
            short8 af[4], bf[4];
#pragma unroll
            for (int ot = 0; ot < 4; ++ot)
                af[ot] = *(const short8*)swzp(As, ow + ot * 16 + ln, sub * 32 + quad * 8);
#pragma unroll
            for (int nt = 0; nt < 4; ++nt)
                bf[nt] = *(const short8*)swzp(Bs, nw + nt * 16 + ln, sub * 32 + quad * 8);
            if (!vpath) {   // acc[ot][nt]: row = o, col = n
#pragma unroll
                for (int ot = 0; ot < 4; ++ot)
#pragma unroll
                    for (int nt = 0; nt < 4; ++nt)
                        acc[ot][nt] = __builtin_amdgcn_mfma_f32_16x16x32_bf16(
                            af[ot], bf[nt], acc[ot][nt], 0, 0, 0);
            } else {        // acc[nt][ot]: row = n, col = o (transposed C)
#pragma unroll
                for (int nt = 0; nt < 4; ++nt)
#pragma unroll
                    for (int ot = 0; ot < 4; ++ot)
                        acc[nt][ot] = __builtin_amdgcn_mfma_f32_16x16x32_bf16(
                            bf[nt], af[ot], acc[nt][ot], 0, 0, 0);
            }
        }
    }

    __syncthreads();                     // staging reads done; alias lds
    if (!vpath) {
        // ---- Q/K epilogue: Ct [n][136 o-stride], vectorized both ways ----
        ushort* Ct = lds;
        const float sc = (o0 < 512) ? QSCALE : 1.0f;
#pragma unroll
        for (int ot = 0; ot < 4; ++ot) {
            float bs[4];
#pragma unroll
            for (int rg = 0; rg < 4; ++rg)
                bs[rg] = bias[o0 + ow + ot * 16 + quad * 4 + rg];
#pragma unroll
            for (int nt = 0; nt < 4; ++nt) {
                ushort4 u;
                u.x = f2b((acc[ot][nt][0] + bs[0]) * sc);
                u.y = f2b((acc[ot][nt][1] + bs[1]) * sc);
                u.z = f2b((acc[ot][nt][2] + bs[2]) * sc);
                u.w = f2b((acc[ot][nt][3] + bs[3]) * sc);
                *(ushort4*)&Ct[(nw + nt * 16 + ln) * 136 + ow + ot * 16 + quad * 4] = u;
            }
        }
        __syncthreads();
        ushort* dst; int obase;
        if (o0 < 512) { dst = qb; obase = o0; }
        else          { dst = kb; obase = o0 - 512; }
        const int rn = t >> 1, hf = t & 1;
        const int bh = b * 8 + (obase >> 6) + hf;
        ushort* drow = &dst[(bh * Np + n0 + rn) << 6];
        const ushort* srow = &Ct[rn * 136 + hf * 64];
#pragma unroll
        for (int s = 0; s < 8; ++s)
            *(uint4*)(drow + s * 8) = *(const uint4*)(srow + s * 8);
    } else {
        // ---- V epilogue: Ct [o][136 n-stride] (rows = d), then [bh][d][n] ----
        ushort* Ct = lds;
#pragma unroll
        for (int ot = 0; ot < 4; ++ot) {
            const float bo = bias[o0 + ow + ot * 16 + ln];
#pragma unroll
            for (int nt = 0; nt < 4; ++nt) {
                ushort4 u;
                u.x = f2b(acc[nt][ot][0] + bo);
                u.y = f2b(acc[nt][ot][1] + bo);
                u.z = f2b(acc[nt][ot][2] + bo);
                u.w = f2b(acc[nt][ot][3] + bo);
                *(ushort4*)&Ct[(ow + ot * 16 + ln) * 136 + nw + nt * 16 + quad * 4] = u;
            }
        }
        __syncthreads();
        const int o_l = t >> 1, nh = (t & 1) * 64;
        const int bh = b * 8 + ((o0 - 1024) >> 6) + (o_l >> 6);
        ushort* drow = &vb[((size_t)bh << 16) + ((o_l & 63) << 10) + n0 + nh];
        const ushort* srow = &Ct[o_l * 136 + nh];
#pragma unroll
        for (int s = 0; s < 8; ++s)
            *(uint4*)(drow + s * 8) = *(const uint4*)(srow + s * 8);
    }
}

// ---------------------------------------------------------------------------
// Kernel 2: causal flash attention — r3 skeleton + global_load_lds staging.
//  * 64 q-rows/block, 4 waves, 2048 blocks, plain __syncthreads.
//  * K [k][64] and V^T [d][64] staged via global_load_lds 16B into linear
//    LDS; XOR swizzle folded into per-lane global source; swzp reads.
//  * O^T = mfma(Vfrag, Pfrag): per-lane softmax state, 8B vector epilogue.
//  * deferred rescale (THR=8, log2 domain) + v_cvt_pk_bf16_f32 P-packing.
// ---------------------------------------------------------------------------
__global__ __launch_bounds__(256, 6)
void attn(const ushort* __restrict__ qb, const ushort* __restrict__ kb,
          const ushort* __restrict__ vt, ushort* __restrict__ ob)
{
    __shared__ ushort Ks[64 * 64];   // [k][d], linear+swizzled data (8 KB)
    __shared__ ushort Vt[64 * 64];   // [d][k], linear+swizzled data (8 KB)
    __shared__ ushort Ps[64 * 72];   // [q][k] wave-private; Q-alias in prologue

    const int t    = threadIdx.x;
    const int w    = t >> 6;
    const int lane = t & 63;
    const int quad = lane >> 4;
    const int ln   = lane & 15;
    const int bh   = blockIdx.x & 127;
    const int qt   = 15 - (int)(blockIdx.x >> 7);   // heavy blocks first
    const int q0   = qt * 64;

    const ushort* __restrict__ kbh = kb + ((size_t)(bh * Np) << 6);
    const ushort* __restrict__ vbh = vt + ((size_t)bh << 16);

    {   // stage Q tile into Ps alias (dead after frag reads below)
        const int r = t & 63, seg = t >> 6;
        const ushort* src = &qb[((size_t)(bh * Np + q0 + r) << 6) + seg * 16];
        *(uint4*)&Ps[r * 72 + seg * 16]     = *(const uint4*)src;
        *(uint4*)&Ps[r * 72 + seg * 16 + 8] = *(const uint4*)(src + 8);
    }
    __syncthreads();

    const short8 qa0 = *(const short8*)&Ps[(w * 16 + ln) * 72 + quad * 8];
    const short8 qa1 = *(const short8*)&Ps[(w * 16 + ln) * 72 + 32 + quad * 8];

    f4 o_[4];
#pragma unroll
    for (int nt = 0; nt < 4; ++nt) o_[nt] = (f4){0.f, 0.f, 0.f, 0.f};
    float m = -INFINITY, l = 0.f;        // state for q = qrow (per lane)

    const int r8  = lane >> 3;                      // staging source mapping
    const int c16 = ((lane & 7) ^ r8) << 3;
    const int prow = (w * 16 + ln) * 72;
    const int qrow = q0 + w * 16 + ln;   // lane's q row (absolute)

    for (int kt = 0; kt <= qt; ++kt) {
        const int k0 = kt * 64;
        __syncthreads();                 // all reads of previous tile done
#pragma unroll
        for (int j = 0; j < 2; ++j) {    // wave w stages K/V chunks 2w, 2w+1
            const int ch  = w * 2 + j;
            const int row = ch * 8 + r8;
            gl16(&kbh[((k0 + row) << 6) + c16],               &Ks[ch * 512]);
            gl16(&vbh[((size_t)row << 10) + k0 + c16],        &Vt[ch * 512]);
        }
        __syncthreads();                 // drains vmcnt -> tile visible

        const bool diag = (kt == qt);

        // ---- S^T = K Q^T : rows k = mt*16+quad*4+rg, col q = ln (log2 dom.)
        f4 st[4];
#pragma unroll
        for (int mt = 0; mt < 4; ++mt) st[mt] = (f4){0.f, 0.f, 0.f, 0.f};
#pragma unroll
        for (int mt = 0; mt < 4; ++mt) {
            if (diag && mt > w) continue;   // fully-masked tile (wave-uniform)
            const short8 ka0 = *(const short8*)swzp(Ks, mt * 16 + ln, quad * 8);
            const short8 ka1 = *(const short8*)swzp(Ks, mt * 16 + ln, 32 + quad * 8);
            st[mt] = __builtin_amdgcn_mfma_f32_16x16x32_bf16(ka0, qa0, st[mt], 0, 0, 0);
            st[mt] = __builtin_amdgcn_mfma_f32_16x16x32_bf16(ka1, qa1, st[mt], 0, 0, 0);
        }

        if (diag) {   // mask k > q
#pragma unroll
            for (int mt = 0; mt < 4; ++mt)
#pragma unroll
                for (int rg = 0; rg < 4; ++rg)
                    if (k0 + mt * 16 + quad * 4 + rg > qrow) st[mt][rg] = -INFINITY;
        }

        // ---- online softmax (log2 domain), deferred rescale THR=8
        float mx = st[0][0];
#pragma unroll
        for (int mt = 0; mt < 4; ++mt)
#pragma unroll
            for (int rg = 0; rg < 4; ++rg) mx = fmaxf(mx, st[mt][rg]);
        mx = fmaxf(mx, __shfl_xor(mx, 16));
        mx = fmaxf(mx, __shfl_xor(mx, 32));

        if (!__all(mx <= m + 8.f)) {
            const float mn = fmaxf(m, mx);
            const float al = EXP2(m - mn);   // first tile: exp2(-inf) = 0
            m = mn; l *= al;
#pragma unroll
            for (int nt = 0; nt < 4; ++nt)
#pragma unroll
                for (int rg = 0; rg < 4; ++rg) o_[nt][rg] *= al;   // col = own q
        }

        float rs = 0.f;
#pragma unroll
        for (int mt = 0; mt < 4; ++mt) {
            const float p0 = EXP2(st[mt][0] - m);
            const float p1 = EXP2(st[mt][1] - m);
            const float p2 = EXP2(st[mt][2] - m);
            const float p3 = EXP2(st[mt][3] - m);
            rs += (p0 + p1) + (p2 + p3);
            uint2 u; u.x = cvtpk(p0, p1); u.y = cvtpk(p2, p3);
            *(uint2*)&Ps[prow + mt * 16 + quad * 4] = u;
        }
        rs += __shfl_xor(rs, 16);
        rs += __shfl_xor(rs, 32);
        l += rs;

        // ---- O^T += V P : A = V frag (rows d), B = P frag (rows q, own wave)
#pragma unroll
        for (int ks = 0; ks < 2; ++ks) {
            if (diag && w * 16 + 15 < ks * 32) continue;   // zero P half
            const short8 pa = *(const short8*)&Ps[prow + ks * 32 + quad * 8];
#pragma unroll
            for (int nt = 0; nt < 4; ++nt) {
                const short8 vf = *(const short8*)swzp(Vt, nt * 16 + ln, ks * 32 + quad * 8);
                o_[nt] = __builtin_amdgcn_mfma_f32_16x16x32_bf16(vf, pa, o_[nt], 0, 0, 0);
            }
        }
    }

    // ---- epilogue: O^T rows d = nt*16+quad*4+rg, col q = own lane's row
    const float li = 1.0f / l;
    ushort* orow = &ob[(size_t)(bh * Np + qrow) << 6];
#pragma unroll
    for (int nt = 0; nt < 4; ++nt) {
        uint2 u;
        u.x = cvtpk(o_[nt][0] * li, o_[nt][1] * li);
        u.y = cvtpk(o_[nt][2] * li, o_[nt][3] * li);
        *(uint2*)(orow + nt * 16 + quad * 4) = u;
    }
}

// ---------------------------------------------------------------------------
// Kernel 3: projection GEMM, bf16 MFMA, 64(o) x 128(n) tile, BK=64,
// global_load_lds staging (linear LDS + swizzled source + swzp reads).
// Grid 512 blocks. Wave w owns n strip [w*32, w*32+32).
// ---------------------------------------------------------------------------
__global__ __launch_bounds__(256)
void proj_gemm(const ushort* __restrict__ obuf, const ushort* __restrict__ pwb,
               const float* __restrict__ bias, float* __restrict__ out)
{
    __shared__ ushort As[64 * 64];    // pw [o][k]        (8 KB)
    __shared__ ushort Bs[128 * 64];   // attn-out [n][k] (16 KB)

    const int t = threadIdx.x;
    const int w = t >> 6, lane = t & 63, quad = lane >> 4, ln = lane & 15;
    const int n0 = blockIdx.x * 128;
    const int o0 = blockIdx.y * 64;
    const int b  = blockIdx.z;
    const int nw = w * 32;

    const int r8  = lane >> 3;
    const int c16 = ((lane & 7) ^ r8) << 3;

    f4 acc[4][2];
#pragma unroll
    for (int i = 0; i < 4; ++i)
#pragma unroll
        for (int j = 0; j < 2; ++j) acc[i][j] = (f4){0.f, 0.f, 0.f, 0.f};

    for (int k0 = 0; k0 < 512; k0 += 64) {
        __syncthreads();
        {   // A: 8 chunks (wave w: 2w,2w+1); B: 16 chunks (wave w: 4w..4w+3)
            const int head = k0 >> 6;
#pragma unroll
            for (int j = 0; j < 2; ++j) {
                const int ch = w * 2 + j, row = ch * 8 + r8;
                gl16(&pwb[(o0 + row) * 512 + k0 + c16], &As[ch * 512]);
            }
#pragma unroll
            for (int j = 0; j < 4; ++j) {
                const int ch = w * 4 + j, row = ch * 8 + r8;
                gl16(&obuf[(((b * 8 + head) * Np + n0 + row) << 6) + c16], &Bs[ch * 512]);
            }
        }
        __syncthreads();                 // drains vmcnt -> tile visible
#pragma unroll
        for (int sub = 0; sub < 2; ++sub) {
            short8 af[4], bf[2];
#pragma unroll
            for (int ot = 0; ot < 4; ++ot)
                af[ot] = *(const short8*)swzp(As, ot * 16 + ln, sub * 32 + quad * 8);
#pragma unroll
            for (int nt = 0; nt < 2; ++nt)
                bf[nt] = *(const short8*)swzp(Bs, nw + nt * 16 + ln, sub * 32 + quad * 8);
#pragma unroll
            for (int ot = 0; ot < 4; ++ot)
#pragma unroll
                for (int nt = 0; nt < 2; ++nt)
                    acc[ot][nt] = __builtin_amdgcn_mfma_f32_16x16x32_bf16(
                        af[ot], bf[nt], acc[ot][nt], 0, 0, 0);
        }
    }

    // epilogue: direct fp32 stores (16-lane 64B segments), bias added
#pragma unroll
    for (int ot = 0; ot < 4; ++ot) {
#pragma unroll
        for (int rg = 0; rg < 4; ++rg) {
            const int oo = o0 + ot * 16 + quad * 4 + rg;
            const float pb = bias[oo];
            float* drow = &out[((b << 8) + oo) << 10];
#pragma unroll
            for (int nt = 0; nt < 2; ++nt)
                drow[n0 + nw + nt * 16 + ln] = acc[ot][nt][rg] + pb;
        }
    }
}

// ---------------------------------------------------------------------------
extern "C" void kernel_launch(void* const* d_in, const int* in_sizes, int n_in,
                              void* d_out, int out_size, void* d_ws, size_t ws_size,
                              hipStream_t stream)
{
    const float* x   = (const float*)d_in[0];   // [16,256,1024]
    const float* qw  = (const float*)d_in[1];   // [1536,256]
    const float* qbb = (const float*)d_in[2];   // [1536]
    const float* pw  = (const float*)d_in[3];   // [256,512]
    const float* pb  = (const float*)d_in[4];   // [256]
    float* out = (float*)d_out;                 // [16,256,1024]

    // workspace (all bf16): q/k [bh][n][64], v TRANSPOSED [bh][64][n],
    // attn-out [bh][n][64]; xb [b][n][c]; weights.
    const size_t per = (size_t)Bsz * 8 * Np * 64;
    ushort* qbuf = (ushort*)d_ws;
    ushort* kbuf = qbuf + per;
    ushort* vbuf = kbuf + per;
    ushort* obuf = vbuf + per;
    ushort* xb   = obuf + per;
    ushort* qwb  = xb + (size_t)Bsz * Np * Cin;
    ushort* pwb  = qwb + 1536 * Cin;

    cast_xw<<<dim3(16, 5, Bsz), 256, 0, stream>>>(x, qw, pw, xb, qwb, pwb);
    qkv_gemm<<<dim3(8, 12, Bsz), 256, 0, stream>>>(xb, qwb, qbb, qbuf, kbuf, vbuf);
    // 2048 blocks = 128 bh x 16 q-tiles of 64 rows; heavy (high qt) first.
    attn<<<dim3(128 * 16), 256, 0, stream>>>(qbuf, kbuf, vbuf, obuf);
    proj_gemm<<<dim3(8, 4, Bsz), 256, 0, stream>>>(obuf, pwb, pb, out);
}